// Round 3
// baseline (776.151 us; speedup 1.0000x reference)
//
#include <hip/hip_runtime.h>
#include <hip/hip_bf16.h>

// CrossChannelAttention: B=2, C=64, H=W=96 -> N=9216, NF=192, RD=24.
// k_qkv (MFMA projections) -> k_attn (S key-segments, flash partials) ->
// k_comb (sum/normalize/residual).
// k_attn v3: 512 threads = 8 waves x 16 q-rows; 128-key super-tiles;
// QK = 16x16x32 bf16 (swapped), PV = MX-scaled 16x16x128 fp8 (scales=1.0).
// Low register pressure (48-reg accumulator) -> 4 waves/SIMD.

#define NPIX 9216
#define NKT 144     // 64-key tiles (k_qkv granularity)
#define QT128 72    // 128-row q-tiles per batch

typedef unsigned short ushort_t;
typedef __attribute__((ext_vector_type(8))) short bf16x8;
typedef __attribute__((ext_vector_type(4))) float f32x4;
typedef __attribute__((ext_vector_type(16))) float f32x16;
typedef __attribute__((ext_vector_type(8))) int int8v;
typedef __attribute__((ext_vector_type(4))) unsigned int uint4v;

__device__ inline ushort_t f2bf(float x) {
  __hip_bfloat16 h = __float2bfloat16(x);
  return *reinterpret_cast<ushort_t*>(&h);
}
__device__ inline float bf2f(ushort_t u) {
  unsigned v = ((unsigned)u) << 16;
  return *reinterpret_cast<float*>(&v);
}
__device__ inline float fast_exp2(float x) {
#if __has_builtin(__builtin_amdgcn_exp2f)
  return __builtin_amdgcn_exp2f(x);
#else
  return exp2f(x);
#endif
}
// XOR-permute 4 dwords: y[p] = x[p ^ gg]
__device__ inline uint4v xorperm4(uint4v x, int gg) {
  uint4v a; a[0] = x[1]; a[1] = x[0]; a[2] = x[3]; a[3] = x[2];
  uint4v y = (gg & 1) ? a : x;
  uint4v b; b[0] = y[2]; b[1] = y[3]; b[2] = y[0]; b[3] = y[1];
  return (gg & 2) ? b : y;
}

// ---------------- kernel 0: pack W_cat (256x192 bf16) + bias_cat ----------
__global__ void k_prep(const float* __restrict__ Wq, const float* __restrict__ bq,
                       const float* __restrict__ Wk, const float* __restrict__ bk,
                       const float* __restrict__ Wv, const float* __restrict__ bv,
                       ushort_t* __restrict__ Wbf, float* __restrict__ bias) {
  const float LOG2E = 1.4426950408889634f;
  int idx = blockIdx.x * 256 + threadIdx.x;
  if (idx < 256 * 192) {
    int o = idx / 192, c = idx % 192;
    float v = 0.f;
    if (o < 24) v = Wq[o * 192 + c] * LOG2E;
    else if (o < 48) v = Wk[(o - 24) * 192 + c];
    else if (o < 240) v = Wv[(o - 48) * 192 + c];
    Wbf[idx] = f2bf(v);
  }
  if (idx < 256) {
    float v = 0.f;
    if (idx < 24) v = bq[idx] * LOG2E;
    else if (idx < 48) v = bk[idx - 24];
    else if (idx < 240) v = bv[idx - 48];
    bias[idx] = v;
  }
}

// ---------------- kernel 1: qkv = W_cat . rgb  (MFMA 32x32x16 bf16) -------
// q_ws,k_ws: (B,N,32) bf16 rows (cols 24..31 zeroed). v_ws: (B,192,N) fp8 e4m3.
__global__ __launch_bounds__(256, 2)
void k_qkv(const float* __restrict__ rIn, const float* __restrict__ gIn,
           const float* __restrict__ bIn,
           const ushort_t* __restrict__ Wbf, const float* __restrict__ bias,
           ushort_t* __restrict__ q_ws, ushort_t* __restrict__ k_ws,
           unsigned char* __restrict__ v_ws) {
  __shared__ __align__(16) ushort_t lds[64 * 200];  // [n][c] transposed tile
  int blk = blockIdx.x;
  int bb = blk / NKT, nt = blk % NKT;
  int n0 = nt * 64;
  int t = threadIdx.x;
  {
    int n4 = (t & 15) * 4;
    int c0 = (t >> 4) * 2;
#pragma unroll
    for (int it = 0; it < 6; ++it) {
      int c = c0 + it * 32;
      int color = c >> 6, cw = c & 63;
      const float* base = color == 0 ? rIn : (color == 1 ? gIn : bIn);
      const float* p0 = base + ((size_t)bb * 64 + cw) * NPIX + n0 + n4;
      float4 va = *(const float4*)p0;
      float4 vb = *(const float4*)(p0 + NPIX);
      const float* ap = (const float*)&va;
      const float* bp = (const float*)&vb;
#pragma unroll
      for (int j = 0; j < 4; ++j) {
        unsigned u = ((unsigned)f2bf(bp[j]) << 16) | (unsigned)f2bf(ap[j]);
        *(unsigned*)((char*)lds + (size_t)((n4 + j) * 200 + c) * 2) = u;
      }
    }
  }
  __syncthreads();
  int w = t >> 6, l = t & 63, lo = l & 31, h = l >> 5;
  f32x16 acc[2][2] = {{{}, {}}, {{}, {}}};
  int oG[2] = {(2 * w + 0) * 32 + lo, (2 * w + 1) * 32 + lo};
#pragma unroll 1
  for (int cc = 0; cc < 12; ++cc) {
    bf16x8 af[2], bfr[2];
#pragma unroll
    for (int i = 0; i < 2; ++i)
      af[i] = *(const bf16x8*)((const char*)Wbf + (size_t)oG[i] * 384 + cc * 32 + 16 * h);
#pragma unroll
    for (int ns = 0; ns < 2; ++ns)
      bfr[ns] = *(const bf16x8*)((const char*)lds + (size_t)(ns * 32 + lo) * 400 + cc * 32 + 16 * h);
#pragma unroll
    for (int i = 0; i < 2; ++i)
#pragma unroll
      for (int ns = 0; ns < 2; ++ns)
        acc[i][ns] = __builtin_amdgcn_mfma_f32_32x32x16_bf16(af[i], bfr[ns], acc[i][ns], 0, 0, 0);
  }
#pragma unroll
  for (int i = 0; i < 2; ++i) {
    int o = oG[i];
    float bv = bias[o];
#pragma unroll
    for (int ns = 0; ns < 2; ++ns) {
      if (o < 32) {
#pragma unroll
        for (int r = 0; r < 16; ++r) {
          int n = n0 + ns * 32 + (r & 3) + 8 * (r >> 2) + 4 * h;
          ushort_t val = (o < 24) ? f2bf(acc[i][ns][r] + bv) : (ushort_t)0;
          q_ws[((size_t)bb * NPIX + n) * 32 + o] = val;
        }
      }
      if (o >= 24 && o < 56) {
        int kc = o - 24;
#pragma unroll
        for (int r = 0; r < 16; ++r) {
          int n = n0 + ns * 32 + (r & 3) + 8 * (r >> 2) + 4 * h;
          ushort_t val = (o < 48) ? f2bf(acc[i][ns][r] + bv) : (ushort_t)0;
          k_ws[((size_t)bb * NPIX + n) * 32 + kc] = val;
        }
      }
      if (o >= 48 && o < 240) {
        int vc = o - 48;
#pragma unroll
        for (int g2 = 0; g2 < 4; ++g2) {
          int r = g2 * 4;
          int n = n0 + ns * 32 + 8 * g2 + 4 * h;
          unsigned wd = (unsigned)__builtin_amdgcn_cvt_pk_fp8_f32(
              acc[i][ns][r] + bv, acc[i][ns][r + 1] + bv, 0, false);
          wd = (unsigned)__builtin_amdgcn_cvt_pk_fp8_f32(
              acc[i][ns][r + 2] + bv, acc[i][ns][r + 3] + bv, (int)wd, true);
          *(unsigned*)(v_ws + ((size_t)bb * 192 + vc) * NPIX + n) = wd;
        }
      }
    }
  }
}

// ---------------- kernel 2: flash attention, one key segment --------------
// LDS (64KB dbuf): per set: V [g 0..3][j 0..1][c*16 ^ g*32 ^ j*16] (24576 B)
//                          K [dg 0..3][key 0..127][16B ^ dg*16]     (8192 B)
// A-frag keys: slot (g, 4j+s, r) = 32g + 16j + 4(g^s) + r; V rows store
// dword p = keydword (p^g) so B-frags read out in A's order.
__global__ __launch_bounds__(512, 4)
void k_attn(const ushort_t* __restrict__ q_ws, const ushort_t* __restrict__ k_ws,
            const unsigned char* __restrict__ v_ws,
            ushort_t* __restrict__ opart, float* __restrict__ lpart,
            int S, int ktPer) {
  __shared__ __align__(16) char smem[65536];
  int id = blockIdx.x;
  int twoS = 2 * S;
  int e = id % twoS, qt = id / twoS;  // id%8 == segment -> per-XCD K/V locality
  int bb = e / S, sg = e % S;
  int q0 = qt * 128;
  int t = threadIdx.x, w = t >> 6, l = t & 63, ql = l & 15, g = l >> 4;

  const char* qb = (const char*)q_ws + (size_t)bb * NPIX * 64;
  const char* kb = (const char*)k_ws + (size_t)bb * NPIX * 64;
  const unsigned char* vb = v_ws + (size_t)bb * 192 * NPIX;

  bf16x8 qf = *(const bf16x8*)(qb + (size_t)(q0 + w * 16 + ql) * 64 + g * 16);

  // staging maps (per-thread constants)
  int vGo[3], vWo[3], vPg[3];
#pragma unroll
  for (int i = 0; i < 3; ++i) {
    int idx = i * 512 + t;
    int c = idx >> 3, pr = idx & 7;
    int gg = pr >> 1, j = pr & 1;
    vGo[i] = c * NPIX + pr * 16;
    vWo[i] = gg * 6144 + j * 3072 + ((c * 16) ^ (gg * 32) ^ (j * 16));
    vPg[i] = gg;
  }
  int kGo = (t >> 2) * 64 + (t & 3) * 16;
  int kWo = (t & 3) * 2048 + (((t >> 2) * 16) ^ ((t & 3) * 16));
  // read bases
  int krb = g * 2048 + ((ql * 16) ^ (g * 16));                 // + c4*256
  int vrb0 = g * 6144 + ((ql * 16) ^ (g * 32));                // + ct*256
  int vrb1 = g * 6144 + 3072 + ((ql * 16) ^ (g * 32) ^ 16);    // + ct*256

  int kbase = sg * ktPer * 128;
  {  // prologue: stage tile 0 into buffer set 0
    uint4v v0 = *(const uint4v*)(vb + kbase + vGo[0]);
    uint4v v1 = *(const uint4v*)(vb + kbase + vGo[1]);
    uint4v v2 = *(const uint4v*)(vb + kbase + vGo[2]);
    uint4v kk = *(const uint4v*)(kb + (size_t)kbase * 64 + kGo);
    *(uint4v*)(smem + vWo[0]) = xorperm4(v0, vPg[0]);
    *(uint4v*)(smem + vWo[1]) = xorperm4(v1, vPg[1]);
    *(uint4v*)(smem + vWo[2]) = xorperm4(v2, vPg[2]);
    *(uint4v*)(smem + 24576 + kWo) = kk;
  }
  __syncthreads();

  f32x4 oacc[12];
#pragma unroll
  for (int i = 0; i < 12; ++i) oacc[i] = f32x4{0.f, 0.f, 0.f, 0.f};
  float lsum = 0.f;

#pragma unroll 1
  for (int it = 0; it < ktPer; ++it) {
    int par = it & 1;
    const char* vbuf = smem + par * 32768;
    const char* kbuf = vbuf + 24576;
    char* vdst = smem + (par ^ 1) * 32768;
    char* kdst = vdst + 24576;
    uint4v vr0, vr1, vr2, kr;
    bool st = (it + 1 < ktPer);
    if (st) {  // issue next-tile global loads early (hide under compute)
      int kb2 = kbase + (it + 1) * 128;
      vr0 = *(const uint4v*)(vb + kb2 + vGo[0]);
      vr1 = *(const uint4v*)(vb + kb2 + vGo[1]);
      vr2 = *(const uint4v*)(vb + kb2 + vGo[2]);
      kr = *(const uint4v*)(kb + (size_t)kb2 * 64 + kGo);
    }
    // ---- QK: 8 chunks of 16 keys ----
    unsigned u[8];
#pragma unroll
    for (int c4 = 0; c4 < 8; ++c4) {
      bf16x8 kf = *(const bf16x8*)(kbuf + krb + c4 * 256);
      f32x4 s = f32x4{0.f, 0.f, 0.f, 0.f};
      s = __builtin_amdgcn_mfma_f32_16x16x32_bf16(kf, qf, s, 0, 0, 0);
      float p0 = fast_exp2(s[0]), p1 = fast_exp2(s[1]);
      float p2 = fast_exp2(s[2]), p3 = fast_exp2(s[3]);
      lsum += (p0 + p1) + (p2 + p3);
      unsigned uu = (unsigned)__builtin_amdgcn_cvt_pk_fp8_f32(p0, p1, 0, false);
      uu = (unsigned)__builtin_amdgcn_cvt_pk_fp8_f32(p2, p3, (int)uu, true);
      u[c4] = uu;
    }
    // ---- redistribute P to MX A-frag (keys 32g..32g+31 per lane-group) ----
    bool gl = (g < 2), ge = ((g & 1) == 0);
    unsigned pOwn[4], pX2[4];
#pragma unroll
    for (int i2 = 0; i2 < 4; ++i2) {
      unsigned snd = gl ? u[i2 + 4] : u[i2];
      unsigned rcv = __shfl_xor(snd, 32);
      pOwn[i2] = gl ? u[i2] : u[i2 + 4];
      pX2[i2] = rcv;
    }
    int8v A;
#pragma unroll
    for (int j2 = 0; j2 < 2; ++j2) {
      unsigned sA = ge ? pOwn[2 + j2] : pOwn[j2];
      unsigned sB = ge ? pX2[2 + j2] : pX2[j2];
      unsigned rA = __shfl_xor(sA, 16);
      unsigned rB = __shfl_xor(sB, 16);
      unsigned kA = ge ? pOwn[j2] : pOwn[2 + j2];
      unsigned kB = ge ? pX2[j2] : pX2[2 + j2];
      A[4 * j2 + 0] = (int)kA;
      A[4 * j2 + 1] = (int)rA;
      A[4 * j2 + 2] = (int)kB;
      A[4 * j2 + 3] = (int)rB;
    }
    // ---- PV: 12 MX-scaled MFMAs (scales = 1.0) ----
#pragma unroll
    for (int ct = 0; ct < 12; ++ct) {
      uint4v b0 = *(const uint4v*)(vbuf + vrb0 + ct * 256);
      uint4v b1 = *(const uint4v*)(vbuf + vrb1 + ct * 256);
      int8v Bv;
      Bv[0] = (int)b0[0]; Bv[1] = (int)b0[1]; Bv[2] = (int)b0[2]; Bv[3] = (int)b0[3];
      Bv[4] = (int)b1[0]; Bv[5] = (int)b1[1]; Bv[6] = (int)b1[2]; Bv[7] = (int)b1[3];
      oacc[ct] = __builtin_amdgcn_mfma_scale_f32_16x16x128_f8f6f4(
          A, Bv, oacc[ct], 0, 0, 0, 0x7F7F7F7F, 0, 0x7F7F7F7F);
    }
    if (st) {  // late LDS writes into the free buffer set
      *(uint4v*)(vdst + vWo[0]) = xorperm4(vr0, vPg[0]);
      *(uint4v*)(vdst + vWo[1]) = xorperm4(vr1, vPg[1]);
      *(uint4v*)(vdst + vWo[2]) = xorperm4(vr2, vPg[2]);
      *(uint4v*)(kdst + kWo) = kr;
    }
    __syncthreads();
  }

  // lsum: reduce over the 4 lane-groups -> all lanes hold l(q=ql)
  float lt = lsum + __shfl_xor(lsum, 16);
  lt += __shfl_xor(lt, 32);
  if (g == 0)
    lpart[(size_t)(sg * 2 + bb) * NPIX + q0 + w * 16 + ql] = lt;

  // store O partials: lane holds O[q=4g+r][c=ct*16+ql] -> 8B packed stores
  ushort_t* ob = opart + (size_t)(sg * 2 + bb) * 192 * NPIX;
  size_t lane_off = (size_t)ql * NPIX + (q0 + w * 16 + 4 * g);
#pragma unroll
  for (int ct = 0; ct < 12; ++ct) {
    f32x4 o = oacc[ct];
    unsigned long long pk = (unsigned long long)f2bf(o[0])
                          | ((unsigned long long)f2bf(o[1]) << 16)
                          | ((unsigned long long)f2bf(o[2]) << 32)
                          | ((unsigned long long)f2bf(o[3]) << 48);
    *(unsigned long long*)(ob + (size_t)ct * 16 * NPIX + lane_off) = pk;
  }
}

// ---------------- kernel 3: combine partials + residual -------------------
__global__ __launch_bounds__(256, 8)
void k_comb(const ushort_t* __restrict__ opart, const float* __restrict__ lpart,
            const float* __restrict__ rIn, const float* __restrict__ gIn,
            const float* __restrict__ bIn, float* __restrict__ out, int S) {
  int tg = blockIdx.x * 256 + threadIdx.x;   // 442368 threads: (bb,c) x n8
  int n8 = tg % 1152, row = tg / 1152;       // row in [0,384)
  int bb = row / 192, c = row % 192;
  int n = n8 * 8;
  float acc[8] = {0.f, 0.f, 0.f, 0.f, 0.f, 0.f, 0.f, 0.f};
  float lt[8] = {0.f, 0.f, 0.f, 0.f, 0.f, 0.f, 0.f, 0.f};
#pragma unroll 1
  for (int sg = 0; sg < S; ++sg) {
    const ushort_t* p = opart + ((size_t)(sg * 2 + bb) * 192 + c) * NPIX + n;
    uint4v u = *(const uint4v*)p;
    const ushort_t* us = (const ushort_t*)&u;
#pragma unroll
    for (int j = 0; j < 8; ++j) acc[j] += bf2f(us[j]);
    const float* lp = lpart + (size_t)(sg * 2 + bb) * NPIX + n;
    float4 l0 = *(const float4*)lp;
    float4 l1 = *(const float4*)(lp + 4);
    lt[0] += l0.x; lt[1] += l0.y; lt[2] += l0.z; lt[3] += l0.w;
    lt[4] += l1.x; lt[5] += l1.y; lt[6] += l1.z; lt[7] += l1.w;
  }
  int color = c >> 6, cw = c & 63;
  const float* base = color == 0 ? rIn : (color == 1 ? gIn : bIn);
  const float* rp = base + ((size_t)bb * 64 + cw) * NPIX + n;
  float4 r0 = *(const float4*)rp;
  float4 r1 = *(const float4*)(rp + 4);
  float o[8];
  o[0] = r0.x + acc[0] / lt[0]; o[1] = r0.y + acc[1] / lt[1];
  o[2] = r0.z + acc[2] / lt[2]; o[3] = r0.w + acc[3] / lt[3];
  o[4] = r1.x + acc[4] / lt[4]; o[5] = r1.y + acc[5] / lt[5];
  o[6] = r1.z + acc[6] / lt[6]; o[7] = r1.w + acc[7] / lt[7];
  float* op = out + ((size_t)(color * 2 + bb) * 64 + cw) * NPIX + n;
  *(float4*)op = {o[0], o[1], o[2], o[3]};
  *(float4*)(op + 4) = {o[4], o[5], o[6], o[7]};
}

// ---------------- launcher -------------------------------------------------
extern "C" void kernel_launch(void* const* d_in, const int* in_sizes, int n_in,
                              void* d_out, int out_size, void* d_ws, size_t ws_size,
                              hipStream_t stream) {
  const float* r  = (const float*)d_in[0];
  const float* g  = (const float*)d_in[1];
  const float* b  = (const float*)d_in[2];
  const float* Wq = (const float*)d_in[3];
  const float* bq = (const float*)d_in[4];
  const float* Wk = (const float*)d_in[5];
  const float* bk = (const float*)d_in[6];
  const float* Wv = (const float*)d_in[7];
  const float* bv = (const float*)d_in[8];

  char* ws = (char*)d_ws;
  ushort_t* Wbf = (ushort_t*)(ws);                       //  98304 B
  float* bias   = (float*)(ws + 98304);                  //   1024 B
  ushort_t* q_ws = (ushort_t*)(ws + 99328);              // 1179648 B
  ushort_t* k_ws = (ushort_t*)(ws + 99328 + 1179648);    // 1179648 B
  unsigned char* v_ws = (unsigned char*)(ws + 99328 + 2 * 1179648);  // 3538944 B
  const size_t qkvEnd = 99328 + 2 * 1179648 + 3538944;   // 5997568
  const size_t perS = (size_t)2 * 192 * NPIX * 2 + (size_t)2 * NPIX * 4;  // 7151616

  int S = 8;
  while (S > 1 && qkvEnd + (size_t)S * perS > ws_size) S >>= 1;
  size_t opartSz = (size_t)S * 2 * 192 * NPIX * 2;
  ushort_t* opart = (ushort_t*)(ws + qkvEnd);
  float* lpart = (float*)(ws + qkvEnd + opartSz);

  k_prep<<<192, 256, 0, stream>>>(Wq, bq, Wk, bk, Wv, bv, Wbf, bias);
  k_qkv<<<2 * NKT, 256, 0, stream>>>(r, g, b, Wbf, bias, q_ws, k_ws, v_ws);
  k_attn<<<QT128 * 2 * S, 512, 0, stream>>>(q_ws, k_ws, v_ws, opart, lpart, S, QT128 / S * 0 + (QT128 * 2 / (2 * S)) * 0 + (9216 / 128 / S));
  k_comb<<<1728, 256, 0, stream>>>(opart, lpart, r, g, b, (float*)d_out, S);
}

// Round 4
// 127.400 us; speedup vs baseline: 6.0922x; 6.0922x over previous
//
#include <hip/hip_runtime.h>
#include <hip/hip_bf16.h>

// CrossChannelAttention: B=2, C=64, H=W=96 -> N=9216, NF=192, RD=24.
// k_qkv (MFMA projections) -> k_attn (S key-segments, flash partials) ->
// k_comb (sum/normalize/residual).
// k_attn v4: 512 thr = 8 waves x 16 q; 128-key tiles; QK 16x16x32 bf16
// (swapped, K rows permuted in LDS so exp'd P packs directly into the PV
// A-frag -- zero shuffles); PV 48x plain fp8 16x16x32 (A=2,B=2 VGPR).
// Staging via global_load_lds (linear LDS dest, pre-swizzled global src).

#define NPIX 9216
#define NKT 144     // 64-key tiles (k_qkv granularity)
#define QT128 72    // 128-row q-tiles per batch

typedef unsigned short ushort_t;
typedef unsigned long long u64;
typedef __attribute__((ext_vector_type(8))) short bf16x8;
typedef __attribute__((ext_vector_type(4))) float f32x4;
typedef __attribute__((ext_vector_type(16))) float f32x16;
typedef __attribute__((ext_vector_type(4))) unsigned int uint4v;

__device__ inline ushort_t f2bf(float x) {
  __hip_bfloat16 h = __float2bfloat16(x);
  return *reinterpret_cast<ushort_t*>(&h);
}
__device__ inline float bf2f(ushort_t u) {
  unsigned v = ((unsigned)u) << 16;
  return *reinterpret_cast<float*>(&v);
}
__device__ inline float fast_exp2(float x) {
#if __has_builtin(__builtin_amdgcn_exp2f)
  return __builtin_amdgcn_exp2f(x);
#else
  return exp2f(x);
#endif
}
__device__ inline void gload_lds16(const void* g, void* l) {
  __builtin_amdgcn_global_load_lds(
      (const __attribute__((address_space(1))) void*)g,
      (__attribute__((address_space(3))) void*)l, 16, 0, 0);
}

// ---------------- kernel 0: pack W_cat (256x192 bf16) + bias_cat ----------
__global__ void k_prep(const float* __restrict__ Wq, const float* __restrict__ bq,
                       const float* __restrict__ Wk, const float* __restrict__ bk,
                       const float* __restrict__ Wv, const float* __restrict__ bv,
                       ushort_t* __restrict__ Wbf, float* __restrict__ bias) {
  const float LOG2E = 1.4426950408889634f;
  int idx = blockIdx.x * 256 + threadIdx.x;
  if (idx < 256 * 192) {
    int o = idx / 192, c = idx % 192;
    float v = 0.f;
    if (o < 24) v = Wq[o * 192 + c] * LOG2E;
    else if (o < 48) v = Wk[(o - 24) * 192 + c];
    else if (o < 240) v = Wv[(o - 48) * 192 + c];
    Wbf[idx] = f2bf(v);
  }
  if (idx < 256) {
    float v = 0.f;
    if (idx < 24) v = bq[idx] * LOG2E;
    else if (idx < 48) v = bk[idx - 24];
    else if (idx < 240) v = bv[idx - 48];
    bias[idx] = v;
  }
}

// ---------------- kernel 1: qkv = W_cat . rgb  (MFMA 32x32x16 bf16) -------
// q_ws,k_ws: (B,N,32) bf16 rows (cols 24..31 zeroed). v_ws: (B,192,N) fp8 e4m3.
__global__ __launch_bounds__(256, 2)
void k_qkv(const float* __restrict__ rIn, const float* __restrict__ gIn,
           const float* __restrict__ bIn,
           const ushort_t* __restrict__ Wbf, const float* __restrict__ bias,
           ushort_t* __restrict__ q_ws, ushort_t* __restrict__ k_ws,
           unsigned char* __restrict__ v_ws) {
  __shared__ __align__(16) ushort_t lds[64 * 200];  // [n][c] transposed tile
  int blk = blockIdx.x;
  int bb = blk / NKT, nt = blk % NKT;
  int n0 = nt * 64;
  int t = threadIdx.x;
  {
    int n4 = (t & 15) * 4;
    int c0 = (t >> 4) * 2;
#pragma unroll
    for (int it = 0; it < 6; ++it) {
      int c = c0 + it * 32;
      int color = c >> 6, cw = c & 63;
      const float* base = color == 0 ? rIn : (color == 1 ? gIn : bIn);
      const float* p0 = base + ((size_t)bb * 64 + cw) * NPIX + n0 + n4;
      float4 va = *(const float4*)p0;
      float4 vb = *(const float4*)(p0 + NPIX);
      const float* ap = (const float*)&va;
      const float* bp = (const float*)&vb;
#pragma unroll
      for (int j = 0; j < 4; ++j) {
        unsigned u = ((unsigned)f2bf(bp[j]) << 16) | (unsigned)f2bf(ap[j]);
        *(unsigned*)((char*)lds + (size_t)((n4 + j) * 200 + c) * 2) = u;
      }
    }
  }
  __syncthreads();
  int w = t >> 6, l = t & 63, lo = l & 31, h = l >> 5;
  f32x16 acc[2][2] = {{{}, {}}, {{}, {}}};
  int oG[2] = {(2 * w + 0) * 32 + lo, (2 * w + 1) * 32 + lo};
#pragma unroll 1
  for (int cc = 0; cc < 12; ++cc) {
    bf16x8 af[2], bfr[2];
#pragma unroll
    for (int i = 0; i < 2; ++i)
      af[i] = *(const bf16x8*)((const char*)Wbf + (size_t)oG[i] * 384 + cc * 32 + 16 * h);
#pragma unroll
    for (int ns = 0; ns < 2; ++ns)
      bfr[ns] = *(const bf16x8*)((const char*)lds + (size_t)(ns * 32 + lo) * 400 + cc * 32 + 16 * h);
#pragma unroll
    for (int i = 0; i < 2; ++i)
#pragma unroll
      for (int ns = 0; ns < 2; ++ns)
        acc[i][ns] = __builtin_amdgcn_mfma_f32_32x32x16_bf16(af[i], bfr[ns], acc[i][ns], 0, 0, 0);
  }
#pragma unroll
  for (int i = 0; i < 2; ++i) {
    int o = oG[i];
    float bv = bias[o];
#pragma unroll
    for (int ns = 0; ns < 2; ++ns) {
      if (o < 32) {
#pragma unroll
        for (int r = 0; r < 16; ++r) {
          int n = n0 + ns * 32 + (r & 3) + 8 * (r >> 2) + 4 * h;
          ushort_t val = (o < 24) ? f2bf(acc[i][ns][r] + bv) : (ushort_t)0;
          q_ws[((size_t)bb * NPIX + n) * 32 + o] = val;
        }
      }
      if (o >= 24 && o < 56) {
        int kc = o - 24;
#pragma unroll
        for (int r = 0; r < 16; ++r) {
          int n = n0 + ns * 32 + (r & 3) + 8 * (r >> 2) + 4 * h;
          ushort_t val = (o < 48) ? f2bf(acc[i][ns][r] + bv) : (ushort_t)0;
          k_ws[((size_t)bb * NPIX + n) * 32 + kc] = val;
        }
      }
      if (o >= 48 && o < 240) {
        int vc = o - 48;
#pragma unroll
        for (int g2 = 0; g2 < 4; ++g2) {
          int r = g2 * 4;
          int n = n0 + ns * 32 + 8 * g2 + 4 * h;
          unsigned wd = (unsigned)__builtin_amdgcn_cvt_pk_fp8_f32(
              acc[i][ns][r] + bv, acc[i][ns][r + 1] + bv, 0, false);
          wd = (unsigned)__builtin_amdgcn_cvt_pk_fp8_f32(
              acc[i][ns][r + 2] + bv, acc[i][ns][r + 3] + bv, (int)wd, true);
          *(unsigned*)(v_ws + ((size_t)bb * 192 + vc) * NPIX + n) = wd;
        }
      }
    }
  }
}

// ---------------- kernel 2: flash attention, one key segment --------------
// LDS per set (32768B): V [c 0..191][128B keys, 16B-chunk s8 at s8^(c&7)];
//                       K @24576 [slot 0..3][pos 0..127][16B ^ slot*16].
// K pos->global key: kappa = 32*(pos>>5) + 8*((pos>>2)&3) + 4*((pos>>4)&1)
//                            + (pos&3)
// so QK chunk c4=2m+j2 exp-packs directly into PV A dword j2 for slab m.
__global__ __launch_bounds__(512, 4)
void k_attn(const ushort_t* __restrict__ q_ws, const ushort_t* __restrict__ k_ws,
            const unsigned char* __restrict__ v_ws,
            ushort_t* __restrict__ opart, float* __restrict__ lpart,
            int S, int ktPer) {
  __shared__ __align__(16) char smem[65536];
  int id = blockIdx.x;
  int twoS = 2 * S;
  int e = id % twoS, qt = id / twoS;  // id%8 ~ XCD -> per-XCD K/V L2 locality
  int bb = e / S, sg = e % S;
  int q0 = qt * 128;
  int t = threadIdx.x, w = t >> 6, l = t & 63, ql = l & 15, g = l >> 4;

  const char* qb = (const char*)q_ws + (size_t)bb * NPIX * 64;
  const char* kb = (const char*)k_ws + (size_t)bb * NPIX * 64;
  const unsigned char* vb = v_ws + (size_t)bb * 192 * NPIX;

  bf16x8 qf = *(const bf16x8*)(qb + (size_t)(q0 + w * 16 + ql) * 64 + g * 16);

  // staging: global offsets (LDS dest is linear; swizzle folded into source)
  int vgo[3];
#pragma unroll
  for (int i = 0; i < 3; ++i) {
    int idx = i * 512 + t;
    int c = idx >> 3, s8 = idx & 7;
    int g8 = s8 ^ (c & 7);
    vgo[i] = c * NPIX + g8 * 16;
  }
  int slot = t >> 7, pos = (t & 127) ^ (t >> 7);
  int kap = ((pos >> 5) << 5) + (((pos >> 2) & 3) << 3) +
            (((pos >> 4) & 1) << 2) + (pos & 3);
  int kgo = kap * 64 + slot * 16;

  // read offsets
  int kro = g * 2048 + ((ql * 16) ^ (g * 16));  // + c4*256
  int voffm[4];
#pragma unroll
  for (int m = 0; m < 4; ++m)
    voffm[m] = ql * 128 + 8 * (g & 1) + ((((2 * m) + (g >> 1)) ^ (ql & 7)) << 4);

  int kbase = sg * ktPer * 128;
  {  // prologue: stage tile 0 into set 0
    const unsigned char* vp = vb + kbase;
#pragma unroll
    for (int i = 0; i < 3; ++i)
      gload_lds16(vp + vgo[i], smem + (i * 512 + w * 64) * 16);
    gload_lds16(kb + (size_t)kbase * 64 + kgo, smem + 24576 + w * 1024);
  }
  __syncthreads();

  f32x4 oacc[12];
#pragma unroll
  for (int i = 0; i < 12; ++i) oacc[i] = f32x4{0.f, 0.f, 0.f, 0.f};
  float lsum = 0.f;

#pragma unroll 1
  for (int it = 0; it < ktPer; ++it) {
    int par = it & 1;
    const char* vbuf = smem + par * 32768;
    const char* kbuf = vbuf + 24576;
    char* dst = smem + (par ^ 1) * 32768;
    if (it + 1 < ktPer) {  // async prefetch next tile into the free set
      int k1 = kbase + (it + 1) * 128;
      const unsigned char* vp = vb + k1;
#pragma unroll
      for (int i = 0; i < 3; ++i)
        gload_lds16(vp + vgo[i], dst + (i * 512 + w * 64) * 16);
      gload_lds16(kb + (size_t)k1 * 64 + kgo, dst + 24576 + w * 1024);
    }
#pragma unroll
    for (int m = 0; m < 4; ++m) {
      bf16x8 kf0 = *(const bf16x8*)(kbuf + kro + (2 * m) * 256);
      bf16x8 kf1 = *(const bf16x8*)(kbuf + kro + (2 * m + 1) * 256);
      f32x4 s0 = f32x4{0.f, 0.f, 0.f, 0.f};
      f32x4 s1 = f32x4{0.f, 0.f, 0.f, 0.f};
      s0 = __builtin_amdgcn_mfma_f32_16x16x32_bf16(kf0, qf, s0, 0, 0, 0);
      s1 = __builtin_amdgcn_mfma_f32_16x16x32_bf16(kf1, qf, s1, 0, 0, 0);
      float p0 = fast_exp2(s0[0]), p1 = fast_exp2(s0[1]);
      float p2 = fast_exp2(s0[2]), p3 = fast_exp2(s0[3]);
      float p4 = fast_exp2(s1[0]), p5 = fast_exp2(s1[1]);
      float p6 = fast_exp2(s1[2]), p7 = fast_exp2(s1[3]);
      lsum += ((p0 + p1) + (p2 + p3)) + ((p4 + p5) + (p6 + p7));
      unsigned u0 = (unsigned)__builtin_amdgcn_cvt_pk_fp8_f32(p0, p1, 0, false);
      u0 = (unsigned)__builtin_amdgcn_cvt_pk_fp8_f32(p2, p3, (int)u0, true);
      unsigned u1 = (unsigned)__builtin_amdgcn_cvt_pk_fp8_f32(p4, p5, 0, false);
      u1 = (unsigned)__builtin_amdgcn_cvt_pk_fp8_f32(p6, p7, (int)u1, true);
      long A = (long)(((u64)u1 << 32) | (u64)u0);
      const char* vB = vbuf + voffm[m];
#pragma unroll
      for (int ct = 0; ct < 12; ++ct) {
        long Bv = *(const long*)(vB + ct * 2048);
        oacc[ct] = __builtin_amdgcn_mfma_f32_16x16x32_fp8_fp8(A, Bv, oacc[ct], 0, 0, 0);
      }
    }
    __syncthreads();
  }

  // lsum: reduce over 4 lane-groups -> all lanes hold l(q=ql)
  float lt = lsum + __shfl_xor(lsum, 16);
  lt += __shfl_xor(lt, 32);
  if (g == 0)
    lpart[(size_t)(sg * 2 + bb) * NPIX + q0 + w * 16 + ql] = lt;

  // store O partials: lane holds O[q=4g+r][c=ct*16+ql] -> 8B packed stores
  ushort_t* ob = opart + (size_t)(sg * 2 + bb) * 192 * NPIX;
  size_t lane_off = (size_t)ql * NPIX + (q0 + w * 16 + 4 * g);
#pragma unroll
  for (int ct = 0; ct < 12; ++ct) {
    f32x4 o = oacc[ct];
    u64 pk = (u64)f2bf(o[0]) | ((u64)f2bf(o[1]) << 16)
           | ((u64)f2bf(o[2]) << 32) | ((u64)f2bf(o[3]) << 48);
    *(u64*)(ob + (size_t)ct * 16 * NPIX + lane_off) = pk;
  }
}

// ---------------- kernel 3: combine partials + residual -------------------
__global__ __launch_bounds__(256, 8)
void k_comb(const ushort_t* __restrict__ opart, const float* __restrict__ lpart,
            const float* __restrict__ rIn, const float* __restrict__ gIn,
            const float* __restrict__ bIn, float* __restrict__ out, int S) {
  int tg = blockIdx.x * 256 + threadIdx.x;   // 442368 threads: (bb,c) x n8
  int n8 = tg % 1152, row = tg / 1152;       // row in [0,384)
  int bb = row / 192, c = row % 192;
  int n = n8 * 8;
  float acc[8] = {0.f, 0.f, 0.f, 0.f, 0.f, 0.f, 0.f, 0.f};
  float lt[8] = {0.f, 0.f, 0.f, 0.f, 0.f, 0.f, 0.f, 0.f};
#pragma unroll 1
  for (int sg = 0; sg < S; ++sg) {
    const ushort_t* p = opart + ((size_t)(sg * 2 + bb) * 192 + c) * NPIX + n;
    uint4v u = *(const uint4v*)p;
    const ushort_t* us = (const ushort_t*)&u;
#pragma unroll
    for (int j = 0; j < 8; ++j) acc[j] += bf2f(us[j]);
    const float* lp = lpart + (size_t)(sg * 2 + bb) * NPIX + n;
    float4 l0 = *(const float4*)lp;
    float4 l1 = *(const float4*)(lp + 4);
    lt[0] += l0.x; lt[1] += l0.y; lt[2] += l0.z; lt[3] += l0.w;
    lt[4] += l1.x; lt[5] += l1.y; lt[6] += l1.z; lt[7] += l1.w;
  }
  int color = c >> 6, cw = c & 63;
  const float* base = color == 0 ? rIn : (color == 1 ? gIn : bIn);
  const float* rp = base + ((size_t)bb * 64 + cw) * NPIX + n;
  float4 r0 = *(const float4*)rp;
  float4 r1 = *(const float4*)(rp + 4);
  float o[8];
  o[0] = r0.x + acc[0] / lt[0]; o[1] = r0.y + acc[1] / lt[1];
  o[2] = r0.z + acc[2] / lt[2]; o[3] = r0.w + acc[3] / lt[3];
  o[4] = r1.x + acc[4] / lt[4]; o[5] = r1.y + acc[5] / lt[5];
  o[6] = r1.z + acc[6] / lt[6]; o[7] = r1.w + acc[7] / lt[7];
  float* op = out + ((size_t)(color * 2 + bb) * 64 + cw) * NPIX + n;
  *(float4*)op = {o[0], o[1], o[2], o[3]};
  *(float4*)(op + 4) = {o[4], o[5], o[6], o[7]};
}

// ---------------- launcher -------------------------------------------------
extern "C" void kernel_launch(void* const* d_in, const int* in_sizes, int n_in,
                              void* d_out, int out_size, void* d_ws, size_t ws_size,
                              hipStream_t stream) {
  const float* r  = (const float*)d_in[0];
  const float* g  = (const float*)d_in[1];
  const float* b  = (const float*)d_in[2];
  const float* Wq = (const float*)d_in[3];
  const float* bq = (const float*)d_in[4];
  const float* Wk = (const float*)d_in[5];
  const float* bk = (const float*)d_in[6];
  const float* Wv = (const float*)d_in[7];
  const float* bv = (const float*)d_in[8];

  char* ws = (char*)d_ws;
  ushort_t* Wbf = (ushort_t*)(ws);                       //  98304 B
  float* bias   = (float*)(ws + 98304);                  //   1024 B
  ushort_t* q_ws = (ushort_t*)(ws + 99328);              // 1179648 B
  ushort_t* k_ws = (ushort_t*)(ws + 99328 + 1179648);    // 1179648 B
  unsigned char* v_ws = (unsigned char*)(ws + 99328 + 2 * 1179648);  // 3538944 B
  const size_t qkvEnd = 99328 + 2 * 1179648 + 3538944;   // 5997568
  const size_t perS = (size_t)2 * 192 * NPIX * 2 + (size_t)2 * NPIX * 4;  // 7151616

  int S = 8;
  while (S > 1 && qkvEnd + (size_t)S * perS > ws_size) S >>= 1;
  size_t opartSz = (size_t)S * 2 * 192 * NPIX * 2;
  ushort_t* opart = (ushort_t*)(ws + qkvEnd);
  float* lpart = (float*)(ws + qkvEnd + opartSz);

  k_prep<<<192, 256, 0, stream>>>(Wq, bq, Wk, bk, Wv, bv, Wbf, bias);
  k_qkv<<<2 * NKT, 256, 0, stream>>>(r, g, b, Wbf, bias, q_ws, k_ws, v_ws);
  k_attn<<<QT128 * 2 * S, 512, 0, stream>>>(q_ws, k_ws, v_ws, opart, lpart, S, QT128 / S);
  k_comb<<<1728, 256, 0, stream>>>(opart, lpart, r, g, b, (float*)d_out, S);
}